// Round 1
// baseline (9513.533 us; speedup 1.0000x reference)
//
#include <hip/hip_runtime.h>

#define NN 100000
#define EE 1600000
#define DD 128
#define NLAYERS 3
#define BN_EPS 1e-5f
#define SCALING 1.0f

#define BM 64
#define LDSP 132   // padded LDS row stride (132 mod 32 = 4 -> conflict-free column reads)

// ---------------------------------------------------------------------------
// Kernel 1: GINEConv message + scatter-add.  One 32-lane group per edge.
// msg = relu(h[src] + edge_attr[e]);  agg[dst] += msg  (native fp32 atomics)
// ---------------------------------------------------------------------------
__global__ __launch_bounds__(256) void edge_kernel(
    const float* __restrict__ h,
    const float* __restrict__ edge_attr,
    const int* __restrict__ src,
    const int* __restrict__ dst,
    float* __restrict__ agg)
{
    const int lane = threadIdx.x & 31;
    int group = blockIdx.x * 8 + (threadIdx.x >> 5);
    const int ngroups = gridDim.x * 8;
    for (int e = group; e < EE; e += ngroups) {
        const int s = src[e];
        const int d = dst[e];
        float4 hv = ((const float4*)(h + (size_t)s * DD))[lane];
        float4 ev = ((const float4*)(edge_attr + (size_t)e * DD))[lane];
        float4 r;
        r.x = fmaxf(hv.x + ev.x, 0.0f);
        r.y = fmaxf(hv.y + ev.y, 0.0f);
        r.z = fmaxf(hv.z + ev.z, 0.0f);
        r.w = fmaxf(hv.w + ev.w, 0.0f);
        float* ap = agg + (size_t)d * DD + lane * 4;
        unsafeAtomicAdd(ap + 0, r.x);
        unsafeAtomicAdd(ap + 1, r.y);
        unsafeAtomicAdd(ap + 2, r.z);
        unsafeAtomicAdd(ap + 3, r.w);
    }
}

// ---------------------------------------------------------------------------
// Kernel 2: fused  z=(1+eps)*h+agg -> relu(z@W1+b1)@W2+b2 -> v=m*u+x_in
// plus per-column partial sums for BN stats.  64 rows/block, 256 threads,
// each thread computes a 4x8 register tile.  W1/W2 read from global (L2-hot).
// v written in-place over agg.
// ---------------------------------------------------------------------------
__global__ __launch_bounds__(256) void mlp_kernel(
    const float* __restrict__ hin,
    float* aggv,                       // in: agg, out: v (in place, same rows)
    const float* __restrict__ W1,
    const float* __restrict__ b1,
    const float* __restrict__ W2,
    const float* __restrict__ b2,
    const float* __restrict__ mask,
    const float* __restrict__ epsp, int layer,
    float* __restrict__ sums, float* __restrict__ sumsq)
{
    __shared__ float ls[BM * LDSP];    // 33.8 KB: z tile, then reused for t tile
    __shared__ float red[16 * DD];     // 8 KB: cross-thread column reduction
    const int tid = threadIdx.x;
    const int row0 = blockIdx.x * BM;
    const float eps1 = 1.0f + epsp[layer];

    // --- phase 1: build z tile in LDS ---
    for (int i = tid; i < BM * (DD / 4); i += 256) {
        const int r = i >> 5;          // 32 float4 per row
        const int q = i & 31;
        const int gr = row0 + r;
        float4 z = make_float4(0.f, 0.f, 0.f, 0.f);
        if (gr < NN) {
            float4 hv = ((const float4*)(hin + (size_t)gr * DD))[q];
            float4 av = ((const float4*)(aggv + (size_t)gr * DD))[q];
            z.x = fmaf(eps1, hv.x, av.x);
            z.y = fmaf(eps1, hv.y, av.y);
            z.z = fmaf(eps1, hv.z, av.z);
            z.w = fmaf(eps1, hv.w, av.w);
        }
        *(float4*)&ls[r * LDSP + q * 4] = z;
    }
    __syncthreads();

    const int tx = tid & 15;
    const int ty = tid >> 4;
    const int r0 = ty * 4;
    const int c0 = tx * 8;

    float acc[4][8];
    #pragma unroll
    for (int i = 0; i < 4; ++i)
        #pragma unroll
        for (int j = 0; j < 8; ++j) acc[i][j] = 0.f;

    // --- GEMM1: t = z @ W1 ---
    {
        const float* w = W1 + c0;
        #pragma unroll 4
        for (int k = 0; k < DD; ++k) {
            float a[4];
            #pragma unroll
            for (int i = 0; i < 4; ++i) a[i] = ls[(r0 + i) * LDSP + k];
            float4 bA = *(const float4*)(w);
            float4 bB = *(const float4*)(w + 4);
            w += DD;
            float b[8] = {bA.x, bA.y, bA.z, bA.w, bB.x, bB.y, bB.z, bB.w};
            #pragma unroll
            for (int i = 0; i < 4; ++i)
                #pragma unroll
                for (int j = 0; j < 8; ++j)
                    acc[i][j] = fmaf(a[i], b[j], acc[i][j]);
        }
    }

    // bias1 + relu -> t, store t into ls (reuse buffer)
    float4 b1A = *(const float4*)(b1 + c0);
    float4 b1B = *(const float4*)(b1 + c0 + 4);
    const float bias1[8] = {b1A.x, b1A.y, b1A.z, b1A.w, b1B.x, b1B.y, b1B.z, b1B.w};
    __syncthreads();   // all GEMM1 reads of ls complete
    #pragma unroll
    for (int i = 0; i < 4; ++i) {
        float4 t0, t1;
        t0.x = fmaxf(acc[i][0] + bias1[0], 0.f);
        t0.y = fmaxf(acc[i][1] + bias1[1], 0.f);
        t0.z = fmaxf(acc[i][2] + bias1[2], 0.f);
        t0.w = fmaxf(acc[i][3] + bias1[3], 0.f);
        t1.x = fmaxf(acc[i][4] + bias1[4], 0.f);
        t1.y = fmaxf(acc[i][5] + bias1[5], 0.f);
        t1.z = fmaxf(acc[i][6] + bias1[6], 0.f);
        t1.w = fmaxf(acc[i][7] + bias1[7], 0.f);
        *(float4*)&ls[(r0 + i) * LDSP + c0] = t0;
        *(float4*)&ls[(r0 + i) * LDSP + c0 + 4] = t1;
    }
    __syncthreads();

    // --- GEMM2: u = t @ W2 ---
    #pragma unroll
    for (int i = 0; i < 4; ++i)
        #pragma unroll
        for (int j = 0; j < 8; ++j) acc[i][j] = 0.f;
    {
        const float* w = W2 + c0;
        #pragma unroll 4
        for (int k = 0; k < DD; ++k) {
            float a[4];
            #pragma unroll
            for (int i = 0; i < 4; ++i) a[i] = ls[(r0 + i) * LDSP + k];
            float4 bA = *(const float4*)(w);
            float4 bB = *(const float4*)(w + 4);
            w += DD;
            float b[8] = {bA.x, bA.y, bA.z, bA.w, bB.x, bB.y, bB.z, bB.w};
            #pragma unroll
            for (int i = 0; i < 4; ++i)
                #pragma unroll
                for (int j = 0; j < 8; ++j)
                    acc[i][j] = fmaf(a[i], b[j], acc[i][j]);
        }
    }
    float4 b2A = *(const float4*)(b2 + c0);
    float4 b2B = *(const float4*)(b2 + c0 + 4);
    const float bias2[8] = {b2A.x, b2A.y, b2A.z, b2A.w, b2B.x, b2B.y, b2B.z, b2B.w};

    // --- epilogue: v = m * (u + b2) + x_in ; column partials ---
    float ps[8], pss[8];
    #pragma unroll
    for (int j = 0; j < 8; ++j) { ps[j] = 0.f; pss[j] = 0.f; }
    #pragma unroll
    for (int i = 0; i < 4; ++i) {
        const int gr = row0 + r0 + i;
        if (gr < NN) {
            const float mm = SCALING * mask[gr];
            float4 x0 = *(const float4*)(hin + (size_t)gr * DD + c0);
            float4 x1 = *(const float4*)(hin + (size_t)gr * DD + c0 + 4);
            const float xin[8] = {x0.x, x0.y, x0.z, x0.w, x1.x, x1.y, x1.z, x1.w};
            float vv[8];
            #pragma unroll
            for (int j = 0; j < 8; ++j) {
                float val = fmaf(mm, acc[i][j] + bias2[j], xin[j]);
                vv[j] = val;
                ps[j] += val;
                pss[j] = fmaf(val, val, pss[j]);
            }
            *(float4*)(aggv + (size_t)gr * DD + c0)     = make_float4(vv[0], vv[1], vv[2], vv[3]);
            *(float4*)(aggv + (size_t)gr * DD + c0 + 4) = make_float4(vv[4], vv[5], vv[6], vv[7]);
        }
    }

    // --- cross-thread column reduction (16 ty-groups -> 1) ---
    __syncthreads();
    *(float4*)&red[ty * DD + c0]     = make_float4(ps[0], ps[1], ps[2], ps[3]);
    *(float4*)&red[ty * DD + c0 + 4] = make_float4(ps[4], ps[5], ps[6], ps[7]);
    __syncthreads();
    if (tid < DD) {
        float s = 0.f;
        #pragma unroll
        for (int g = 0; g < 16; ++g) s += red[g * DD + tid];
        unsafeAtomicAdd(&sums[tid], s);
    }
    __syncthreads();
    *(float4*)&red[ty * DD + c0]     = make_float4(pss[0], pss[1], pss[2], pss[3]);
    *(float4*)&red[ty * DD + c0 + 4] = make_float4(pss[4], pss[5], pss[6], pss[7]);
    __syncthreads();
    if (tid < DD) {
        float s = 0.f;
        #pragma unroll
        for (int g = 0; g < 16; ++g) s += red[g * DD + tid];
        unsafeAtomicAdd(&sumsq[tid], s);
    }
}

// ---------------------------------------------------------------------------
// Kernel 3: BN stats -> per-column scale/shift (1 block, 128 threads)
// ---------------------------------------------------------------------------
__global__ void bnstats_kernel(
    const float* __restrict__ sums, const float* __restrict__ sumsq,
    const float* __restrict__ gamma, const float* __restrict__ beta,
    float* __restrict__ scale, float* __restrict__ shift)
{
    const int c = threadIdx.x;
    const float inv_n = 1.0f / (float)NN;
    const float mu = sums[c] * inv_n;
    const float var = sumsq[c] * inv_n - mu * mu;
    const float rs = rsqrtf(var + BN_EPS);
    const float sc = gamma[c] * rs;
    scale[c] = sc;
    shift[c] = beta[c] - mu * sc;
}

// ---------------------------------------------------------------------------
// Kernel 4: h = relu(v * scale + shift)
// ---------------------------------------------------------------------------
__global__ __launch_bounds__(256) void bnrelu_kernel(
    const float* __restrict__ v,
    const float* __restrict__ scale, const float* __restrict__ shift,
    float* __restrict__ out)
{
    const int total = NN * (DD / 4);
    for (int i = blockIdx.x * blockDim.x + threadIdx.x; i < total;
         i += gridDim.x * blockDim.x) {
        const int c4 = (i & 31) * 4;
        float4 vv = ((const float4*)v)[i];
        float4 sc = *(const float4*)(scale + c4);
        float4 sh = *(const float4*)(shift + c4);
        float4 o;
        o.x = fmaxf(fmaf(vv.x, sc.x, sh.x), 0.f);
        o.y = fmaxf(fmaf(vv.y, sc.y, sh.y), 0.f);
        o.z = fmaxf(fmaf(vv.z, sc.z, sh.z), 0.f);
        o.w = fmaxf(fmaf(vv.w, sc.w, sh.w), 0.f);
        ((float4*)out)[i] = o;
    }
}

// ---------------------------------------------------------------------------
extern "C" void kernel_launch(void* const* d_in, const int* in_sizes, int n_in,
                              void* d_out, int out_size, void* d_ws, size_t ws_size,
                              hipStream_t stream) {
    const float* x         = (const float*)d_in[0];
    const float* edge_attr = (const float*)d_in[1];
    const float* masks     = (const float*)d_in[2];
    const int*   edge_idx  = (const int*)d_in[3];
    const float* eps       = (const float*)d_in[4];
    const float* W1        = (const float*)d_in[5];
    const float* b1        = (const float*)d_in[6];
    const float* W2        = (const float*)d_in[7];
    const float* b2        = (const float*)d_in[8];
    const float* gamma     = (const float*)d_in[9];
    const float* beta      = (const float*)d_in[10];
    float* out = (float*)d_out;

    const size_t nd_bytes = (size_t)NN * DD * sizeof(float);
    float* agg   = (float*)d_ws;                               // 51.2 MB (agg, then v in-place)
    float* hbuf  = (float*)((char*)d_ws + nd_bytes);           // 51.2 MB
    float* stats = (float*)((char*)d_ws + 2 * nd_bytes);       // sums|sumsq|scale|shift
    float* sums  = stats;
    float* sumsq = stats + DD;
    float* scale = stats + 2 * DD;
    float* shift = stats + 3 * DD;

    const int* src = edge_idx;
    const int* dst = edge_idx + EE;

    for (int l = 0; l < NLAYERS; ++l) {
        const float* hin = (l == 0) ? x : hbuf;
        float* hout = (l == NLAYERS - 1) ? out : hbuf;

        hipMemsetAsync(agg, 0, nd_bytes, stream);
        hipMemsetAsync(stats, 0, 2 * DD * sizeof(float), stream);

        edge_kernel<<<4096, 256, 0, stream>>>(hin, edge_attr, src, dst, agg);

        mlp_kernel<<<(NN + BM - 1) / BM, 256, 0, stream>>>(
            hin, agg, W1 + (size_t)l * DD * DD, b1 + (size_t)l * DD,
            W2 + (size_t)l * DD * DD, b2 + (size_t)l * DD,
            masks + (size_t)l * NN, eps, l, sums, sumsq);

        bnstats_kernel<<<1, DD, 0, stream>>>(sums, sumsq,
            gamma + (size_t)l * DD, beta + (size_t)l * DD, scale, shift);

        bnrelu_kernel<<<2048, 256, 0, stream>>>(agg, scale, shift, hout);
    }
}

// Round 2
// 2584.608 us; speedup vs baseline: 3.6808x; 3.6808x over previous
//
#include <hip/hip_runtime.h>

#define NN 100000
#define EE 1600000
#define DD 128
#define NLAYERS 3
#define BN_EPS 1e-5f
#define SCALING 1.0f

#define BM 64
#define LDSP 132   // padded LDS row stride (132 mod 32 = 4 -> conflict-free column reads)

// ===========================================================================
// CSR build (once per call): counts -> exclusive scan -> fill (eid, src) pairs
// ===========================================================================
__global__ __launch_bounds__(256) void count_kernel(
    const int* __restrict__ dst, int* __restrict__ counts)
{
    for (int e = blockIdx.x * blockDim.x + threadIdx.x; e < EE;
         e += gridDim.x * blockDim.x)
        atomicAdd(&counts[dst[e]], 1);
}

// single-block exclusive scan of counts[NN] -> rowStart, cursor
__global__ __launch_bounds__(1024) void scan_kernel(
    const int* __restrict__ counts,
    int* __restrict__ rowStart, int* __restrict__ cursor)
{
    __shared__ int lsum[1024];
    const int tid = threadIdx.x;
    const int chunk = (NN + 1023) / 1024;   // 98
    const int base = tid * chunk;
    int s = 0;
    for (int i = 0; i < chunk; ++i) {
        const int idx = base + i;
        if (idx < NN) s += counts[idx];
    }
    lsum[tid] = s;
    __syncthreads();
    // Hillis-Steele inclusive scan
    for (int off = 1; off < 1024; off <<= 1) {
        int v = (tid >= off) ? lsum[tid - off] : 0;
        __syncthreads();
        lsum[tid] += v;
        __syncthreads();
    }
    int run = (tid == 0) ? 0 : lsum[tid - 1];
    for (int i = 0; i < chunk; ++i) {
        const int idx = base + i;
        if (idx < NN) {
            rowStart[idx] = run;
            cursor[idx] = run;
            run += counts[idx];
        }
    }
}

__global__ __launch_bounds__(256) void fill_kernel(
    const int* __restrict__ src, const int* __restrict__ dst,
    int* __restrict__ cursor, int2* __restrict__ eidsrc)
{
    for (int e = blockIdx.x * blockDim.x + threadIdx.x; e < EE;
         e += gridDim.x * blockDim.x) {
        const int p = atomicAdd(&cursor[dst[e]], 1);
        eidsrc[p] = make_int2(e, src[e]);
    }
}

// ===========================================================================
// Gather-style aggregate: one 32-lane group per dst node.
// agg[n] = sum_{e in CSR row n} relu(h[src_e] + edge_attr[e])
// ===========================================================================
__global__ __launch_bounds__(256) void agg_kernel(
    const float* __restrict__ h,
    const float* __restrict__ edge_attr,
    const int* __restrict__ rowStart,
    const int* __restrict__ counts,
    const int2* __restrict__ eidsrc,
    float* __restrict__ agg)
{
    const int lane = threadIdx.x & 31;
    const int node = blockIdx.x * 8 + (threadIdx.x >> 5);
    if (node >= NN) return;
    const int start = rowStart[node];
    const int cnt = counts[node];

    float4 acc = make_float4(0.f, 0.f, 0.f, 0.f);
    int i = 0;
    for (; i + 1 < cnt; i += 2) {
        const int2 a = eidsrc[start + i];
        const int2 b = eidsrc[start + i + 1];
        float4 ha = ((const float4*)(h + (size_t)a.y * DD))[lane];
        float4 ea = ((const float4*)(edge_attr + (size_t)a.x * DD))[lane];
        float4 hb = ((const float4*)(h + (size_t)b.y * DD))[lane];
        float4 eb = ((const float4*)(edge_attr + (size_t)b.x * DD))[lane];
        acc.x += fmaxf(ha.x + ea.x, 0.f) + fmaxf(hb.x + eb.x, 0.f);
        acc.y += fmaxf(ha.y + ea.y, 0.f) + fmaxf(hb.y + eb.y, 0.f);
        acc.z += fmaxf(ha.z + ea.z, 0.f) + fmaxf(hb.z + eb.z, 0.f);
        acc.w += fmaxf(ha.w + ea.w, 0.f) + fmaxf(hb.w + eb.w, 0.f);
    }
    if (i < cnt) {
        const int2 a = eidsrc[start + i];
        float4 ha = ((const float4*)(h + (size_t)a.y * DD))[lane];
        float4 ea = ((const float4*)(edge_attr + (size_t)a.x * DD))[lane];
        acc.x += fmaxf(ha.x + ea.x, 0.f);
        acc.y += fmaxf(ha.y + ea.y, 0.f);
        acc.z += fmaxf(ha.z + ea.z, 0.f);
        acc.w += fmaxf(ha.w + ea.w, 0.f);
    }
    ((float4*)(agg + (size_t)node * DD))[lane] = acc;
}

// ===========================================================================
// Kernel 2: fused  z=(1+eps)*h+agg -> relu(z@W1+b1)@W2+b2 -> v=m*u+x_in
// plus per-column partial sums for BN stats.  64 rows/block, 256 threads,
// 4x8 register tile per thread.  v written in-place over agg.
// ===========================================================================
__global__ __launch_bounds__(256) void mlp_kernel(
    const float* __restrict__ hin,
    float* aggv,
    const float* __restrict__ W1,
    const float* __restrict__ b1,
    const float* __restrict__ W2,
    const float* __restrict__ b2,
    const float* __restrict__ mask,
    const float* __restrict__ epsp, int layer,
    float* __restrict__ sums, float* __restrict__ sumsq)
{
    __shared__ float ls[BM * LDSP];
    __shared__ float red[16 * DD];
    const int tid = threadIdx.x;
    const int row0 = blockIdx.x * BM;
    const float eps1 = 1.0f + epsp[layer];

    // --- phase 1: build z tile in LDS ---
    for (int i = tid; i < BM * (DD / 4); i += 256) {
        const int r = i >> 5;
        const int q = i & 31;
        const int gr = row0 + r;
        float4 z = make_float4(0.f, 0.f, 0.f, 0.f);
        if (gr < NN) {
            float4 hv = ((const float4*)(hin + (size_t)gr * DD))[q];
            float4 av = ((const float4*)(aggv + (size_t)gr * DD))[q];
            z.x = fmaf(eps1, hv.x, av.x);
            z.y = fmaf(eps1, hv.y, av.y);
            z.z = fmaf(eps1, hv.z, av.z);
            z.w = fmaf(eps1, hv.w, av.w);
        }
        *(float4*)&ls[r * LDSP + q * 4] = z;
    }
    __syncthreads();

    const int tx = tid & 15;
    const int ty = tid >> 4;
    const int r0 = ty * 4;
    const int c0 = tx * 8;

    float acc[4][8];
    #pragma unroll
    for (int i = 0; i < 4; ++i)
        #pragma unroll
        for (int j = 0; j < 8; ++j) acc[i][j] = 0.f;

    // --- GEMM1: t = z @ W1 ---
    {
        const float* w = W1 + c0;
        #pragma unroll 4
        for (int k = 0; k < DD; ++k) {
            float a[4];
            #pragma unroll
            for (int i = 0; i < 4; ++i) a[i] = ls[(r0 + i) * LDSP + k];
            float4 bA = *(const float4*)(w);
            float4 bB = *(const float4*)(w + 4);
            w += DD;
            float b[8] = {bA.x, bA.y, bA.z, bA.w, bB.x, bB.y, bB.z, bB.w};
            #pragma unroll
            for (int i = 0; i < 4; ++i)
                #pragma unroll
                for (int j = 0; j < 8; ++j)
                    acc[i][j] = fmaf(a[i], b[j], acc[i][j]);
        }
    }

    float4 b1A = *(const float4*)(b1 + c0);
    float4 b1B = *(const float4*)(b1 + c0 + 4);
    const float bias1[8] = {b1A.x, b1A.y, b1A.z, b1A.w, b1B.x, b1B.y, b1B.z, b1B.w};
    __syncthreads();
    #pragma unroll
    for (int i = 0; i < 4; ++i) {
        float4 t0, t1;
        t0.x = fmaxf(acc[i][0] + bias1[0], 0.f);
        t0.y = fmaxf(acc[i][1] + bias1[1], 0.f);
        t0.z = fmaxf(acc[i][2] + bias1[2], 0.f);
        t0.w = fmaxf(acc[i][3] + bias1[3], 0.f);
        t1.x = fmaxf(acc[i][4] + bias1[4], 0.f);
        t1.y = fmaxf(acc[i][5] + bias1[5], 0.f);
        t1.z = fmaxf(acc[i][6] + bias1[6], 0.f);
        t1.w = fmaxf(acc[i][7] + bias1[7], 0.f);
        *(float4*)&ls[(r0 + i) * LDSP + c0] = t0;
        *(float4*)&ls[(r0 + i) * LDSP + c0 + 4] = t1;
    }
    __syncthreads();

    // --- GEMM2: u = t @ W2 ---
    #pragma unroll
    for (int i = 0; i < 4; ++i)
        #pragma unroll
        for (int j = 0; j < 8; ++j) acc[i][j] = 0.f;
    {
        const float* w = W2 + c0;
        #pragma unroll 4
        for (int k = 0; k < DD; ++k) {
            float a[4];
            #pragma unroll
            for (int i = 0; i < 4; ++i) a[i] = ls[(r0 + i) * LDSP + k];
            float4 bA = *(const float4*)(w);
            float4 bB = *(const float4*)(w + 4);
            w += DD;
            float b[8] = {bA.x, bA.y, bA.z, bA.w, bB.x, bB.y, bB.z, bB.w};
            #pragma unroll
            for (int i = 0; i < 4; ++i)
                #pragma unroll
                for (int j = 0; j < 8; ++j)
                    acc[i][j] = fmaf(a[i], b[j], acc[i][j]);
        }
    }
    float4 b2A = *(const float4*)(b2 + c0);
    float4 b2B = *(const float4*)(b2 + c0 + 4);
    const float bias2[8] = {b2A.x, b2A.y, b2A.z, b2A.w, b2B.x, b2B.y, b2B.z, b2B.w};

    // --- epilogue: v = m * (u + b2) + x_in ; column partials ---
    float ps[8], pss[8];
    #pragma unroll
    for (int j = 0; j < 8; ++j) { ps[j] = 0.f; pss[j] = 0.f; }
    #pragma unroll
    for (int i = 0; i < 4; ++i) {
        const int gr = row0 + r0 + i;
        if (gr < NN) {
            const float mm = SCALING * mask[gr];
            float4 x0 = *(const float4*)(hin + (size_t)gr * DD + c0);
            float4 x1 = *(const float4*)(hin + (size_t)gr * DD + c0 + 4);
            const float xin[8] = {x0.x, x0.y, x0.z, x0.w, x1.x, x1.y, x1.z, x1.w};
            float vv[8];
            #pragma unroll
            for (int j = 0; j < 8; ++j) {
                float val = fmaf(mm, acc[i][j] + bias2[j], xin[j]);
                vv[j] = val;
                ps[j] += val;
                pss[j] = fmaf(val, val, pss[j]);
            }
            *(float4*)(aggv + (size_t)gr * DD + c0)     = make_float4(vv[0], vv[1], vv[2], vv[3]);
            *(float4*)(aggv + (size_t)gr * DD + c0 + 4) = make_float4(vv[4], vv[5], vv[6], vv[7]);
        }
    }

    __syncthreads();
    *(float4*)&red[ty * DD + c0]     = make_float4(ps[0], ps[1], ps[2], ps[3]);
    *(float4*)&red[ty * DD + c0 + 4] = make_float4(ps[4], ps[5], ps[6], ps[7]);
    __syncthreads();
    if (tid < DD) {
        float s = 0.f;
        #pragma unroll
        for (int g = 0; g < 16; ++g) s += red[g * DD + tid];
        unsafeAtomicAdd(&sums[tid], s);
    }
    __syncthreads();
    *(float4*)&red[ty * DD + c0]     = make_float4(pss[0], pss[1], pss[2], pss[3]);
    *(float4*)&red[ty * DD + c0 + 4] = make_float4(pss[4], pss[5], pss[6], pss[7]);
    __syncthreads();
    if (tid < DD) {
        float s = 0.f;
        #pragma unroll
        for (int g = 0; g < 16; ++g) s += red[g * DD + tid];
        unsafeAtomicAdd(&sumsq[tid], s);
    }
}

// ===========================================================================
// Kernel 3: BN stats -> per-column scale/shift (1 block, 128 threads)
// ===========================================================================
__global__ void bnstats_kernel(
    const float* __restrict__ sums, const float* __restrict__ sumsq,
    const float* __restrict__ gamma, const float* __restrict__ beta,
    float* __restrict__ scale, float* __restrict__ shift)
{
    const int c = threadIdx.x;
    const float inv_n = 1.0f / (float)NN;
    const float mu = sums[c] * inv_n;
    const float var = sumsq[c] * inv_n - mu * mu;
    const float rs = rsqrtf(var + BN_EPS);
    const float sc = gamma[c] * rs;
    scale[c] = sc;
    shift[c] = beta[c] - mu * sc;
}

// ===========================================================================
// Kernel 4: h = relu(v * scale + shift)
// ===========================================================================
__global__ __launch_bounds__(256) void bnrelu_kernel(
    const float* __restrict__ v,
    const float* __restrict__ scale, const float* __restrict__ shift,
    float* __restrict__ out)
{
    const int total = NN * (DD / 4);
    for (int i = blockIdx.x * blockDim.x + threadIdx.x; i < total;
         i += gridDim.x * blockDim.x) {
        const int c4 = (i & 31) * 4;
        float4 vv = ((const float4*)v)[i];
        float4 sc = *(const float4*)(scale + c4);
        float4 sh = *(const float4*)(shift + c4);
        float4 o;
        o.x = fmaxf(fmaf(vv.x, sc.x, sh.x), 0.f);
        o.y = fmaxf(fmaf(vv.y, sc.y, sh.y), 0.f);
        o.z = fmaxf(fmaf(vv.z, sc.z, sh.z), 0.f);
        o.w = fmaxf(fmaf(vv.w, sc.w, sh.w), 0.f);
        ((float4*)out)[i] = o;
    }
}

// ===========================================================================
extern "C" void kernel_launch(void* const* d_in, const int* in_sizes, int n_in,
                              void* d_out, int out_size, void* d_ws, size_t ws_size,
                              hipStream_t stream) {
    const float* x         = (const float*)d_in[0];
    const float* edge_attr = (const float*)d_in[1];
    const float* masks     = (const float*)d_in[2];
    const int*   edge_idx  = (const int*)d_in[3];
    const float* eps       = (const float*)d_in[4];
    const float* W1        = (const float*)d_in[5];
    const float* b1        = (const float*)d_in[6];
    const float* W2        = (const float*)d_in[7];
    const float* b2        = (const float*)d_in[8];
    const float* gamma     = (const float*)d_in[9];
    const float* beta      = (const float*)d_in[10];
    float* out = (float*)d_out;

    const size_t nd_bytes = (size_t)NN * DD * sizeof(float);  // 51.2 MB

    // workspace layout (all 16B-aligned)
    char* wsp = (char*)d_ws;
    float* agg      = (float*)wsp;                 wsp += nd_bytes;
    float* stats    = (float*)wsp;                 wsp += 4 * DD * sizeof(float);
    int*   counts   = (int*)wsp;                   wsp += NN * sizeof(int);
    int*   rowStart = (int*)wsp;                   wsp += NN * sizeof(int);
    int*   cursor   = (int*)wsp;                   wsp += NN * sizeof(int);
    int2*  eidsrc   = (int2*)wsp;                  wsp += (size_t)EE * sizeof(int2);

    float* sums  = stats;
    float* sumsq = stats + DD;
    float* scale = stats + 2 * DD;
    float* shift = stats + 3 * DD;

    const int* src = edge_idx;
    const int* dst = edge_idx + EE;

    // ---- build CSR once per call ----
    hipMemsetAsync(counts, 0, NN * sizeof(int), stream);
    count_kernel<<<2048, 256, 0, stream>>>(dst, counts);
    scan_kernel<<<1, 1024, 0, stream>>>(counts, rowStart, cursor);
    fill_kernel<<<2048, 256, 0, stream>>>(src, dst, cursor, eidsrc);

    for (int l = 0; l < NLAYERS; ++l) {
        const float* hin = (l == 0) ? x : out;   // d_out doubles as h ping buffer
        float* hout = out;

        hipMemsetAsync(stats, 0, 2 * DD * sizeof(float), stream);

        agg_kernel<<<(NN + 7) / 8, 256, 0, stream>>>(
            hin, edge_attr, rowStart, counts, eidsrc, agg);

        mlp_kernel<<<(NN + BM - 1) / BM, 256, 0, stream>>>(
            hin, agg, W1 + (size_t)l * DD * DD, b1 + (size_t)l * DD,
            W2 + (size_t)l * DD * DD, b2 + (size_t)l * DD,
            masks + (size_t)l * NN, eps, l, sums, sumsq);

        bnstats_kernel<<<1, DD, 0, stream>>>(sums, sumsq,
            gamma + (size_t)l * DD, beta + (size_t)l * DD, scale, shift);

        bnrelu_kernel<<<2048, 256, 0, stream>>>(agg, scale, shift, hout);
    }
}